// Round 7
// baseline (609.811 us; speedup 1.0000x reference)
//
#include <hip/hip_runtime.h>
#include <hip/hip_bf16.h>

#define N_NODES 100000
#define N_EDGES 1600000
#define IN_DIM 128
#define HID_DIM 256
#define LN_EPS 1e-5f
#define NT (N_NODES / 16)   // 6250 16-row tiles, exact

// deg_out hierarchical histogram config
#define NSLICE 32
#define SLICE (N_NODES / NSLICE)       // 3125 nodes per slice
#define NCHUNK_DO 4
#define CHUNK_E (N_EDGES / NCHUNK_DO)  // 400000 edges per chunk

#define EDGE_BLOCKS (N_EDGES / 256)    // 6250, exact
#define HIST_BLOCKS (NCHUNK_DO * NSLICE)  // 128
#define WCVT_BLOCKS 32
#define FCVT_BLOCKS (N_NODES * 32 / 256)  // 12500, exact

typedef short bf16x8 __attribute__((ext_vector_type(8)));
typedef float f32x4  __attribute__((ext_vector_type(4)));

static __device__ __forceinline__ short f2bf(float x) {
    return __builtin_bit_cast(short, __float2bfloat16(x));  // RNE round
}
static __device__ __forceinline__ float bf2f(ushort u) {
    return __builtin_bit_cast(float, ((unsigned)u) << 16);
}

// ---------------------------------------------------------------------------
// Kernel 1 (pre1), fused by block range:
//   [0, 128)        : deg_out hierarchical LDS histogram -> partial_out
//   [128, 160)      : W / skipW -> bf16 MFMA-fragment-major
//   [160, 160+6250) : rank[e] = atomicAdd(&deg_in[dst[e]], 1)
// hist/wcvt blocks first so they overlap the atomic-bound tail.
// ---------------------------------------------------------------------------
__global__ __launch_bounds__(256)
void pre1_kernel(const int* __restrict__ src, const int* __restrict__ dst,
                 unsigned* __restrict__ deg_in, unsigned* __restrict__ rank,
                 unsigned* __restrict__ partial_out,
                 const float* __restrict__ W, const float* __restrict__ sW,
                 ushort* __restrict__ Wfrag, ushort* __restrict__ sWfrag) {
    __shared__ unsigned bins[SLICE];
    const int b = blockIdx.x;
    if (b < HIST_BLOCKS) {
        const int ci = b >> 5;          // edge chunk 0..3
        const int si = b & 31;          // node slice 0..31
        for (int i = threadIdx.x; i < SLICE; i += 256) bins[i] = 0;
        __syncthreads();
        const int s0 = si * SLICE;
        const int4* sp = (const int4*)(src + ci * CHUNK_E);
        for (int i = threadIdx.x; i < CHUNK_E / 4; i += 256) {
            int4 s = sp[i];
            unsigned u0 = (unsigned)(s.x - s0);
            unsigned u1 = (unsigned)(s.y - s0);
            unsigned u2 = (unsigned)(s.z - s0);
            unsigned u3 = (unsigned)(s.w - s0);
            if (u0 < SLICE) atomicAdd(&bins[u0], 1u);
            if (u1 < SLICE) atomicAdd(&bins[u1], 1u);
            if (u2 < SLICE) atomicAdd(&bins[u2], 1u);
            if (u3 < SLICE) atomicAdd(&bins[u3], 1u);
        }
        __syncthreads();
        for (int i = threadIdx.x; i < SLICE; i += 256)
            partial_out[ci * N_NODES + s0 + i] = bins[i];
    } else if (b < HIST_BLOCKS + WCVT_BLOCKS) {
        int tid = (b - HIST_BLOCKS) * 256 + threadIdx.x;   // 0..8191
        const float* srcm = (tid < 4096) ? W : sW;
        ushort* dstm = (tid < 4096) ? Wfrag : sWfrag;
        int u = tid & 4095;
        int lane = u & 63;
        int ks = (u >> 6) & 3;
        int n = u >> 8;
        int c = lane & 15, g = lane >> 4;
        int col = n * 16 + c;
        int k0 = ks * 32 + g * 8;
        ushort4 lo, hi;
        lo.x = (ushort)f2bf(srcm[(size_t)(k0 + 0) * HID_DIM + col]);
        lo.y = (ushort)f2bf(srcm[(size_t)(k0 + 1) * HID_DIM + col]);
        lo.z = (ushort)f2bf(srcm[(size_t)(k0 + 2) * HID_DIM + col]);
        lo.w = (ushort)f2bf(srcm[(size_t)(k0 + 3) * HID_DIM + col]);
        hi.x = (ushort)f2bf(srcm[(size_t)(k0 + 4) * HID_DIM + col]);
        hi.y = (ushort)f2bf(srcm[(size_t)(k0 + 5) * HID_DIM + col]);
        hi.z = (ushort)f2bf(srcm[(size_t)(k0 + 6) * HID_DIM + col]);
        hi.w = (ushort)f2bf(srcm[(size_t)(k0 + 7) * HID_DIM + col]);
        *(ushort4*)(dstm + (size_t)u * 8)     = lo;
        *(ushort4*)(dstm + (size_t)u * 8 + 4) = hi;
    } else {
        int e = (b - HIST_BLOCKS - WCVT_BLOCKS) * 256 + threadIdx.x;  // exact 1.6M
        rank[e] = atomicAdd(&deg_in[dst[e]], 1u);
    }
}

// ---------------------------------------------------------------------------
// Kernel 2: single-block exclusive scan (4 elems/thread) deg_in -> row_ptr
// ---------------------------------------------------------------------------
__global__ __launch_bounds__(1024)
void scan_kernel(const unsigned* __restrict__ deg_in, unsigned* __restrict__ row_ptr) {
    __shared__ unsigned wsum[16];
    __shared__ unsigned carry_s;
    if (threadIdx.x == 0) carry_s = 0;
    __syncthreads();
    const int lane = threadIdx.x & 63;
    const int wid  = threadIdx.x >> 6;
    for (int base = 0; base < N_NODES; base += 4096) {
        int i0 = base + threadIdx.x * 4;
        unsigned d0 = 0, d1 = 0, d2 = 0, d3 = 0;
        if (i0 < N_NODES) {
            uint4 v = *(const uint4*)(deg_in + i0);
            d0 = v.x; d1 = v.y; d2 = v.z; d3 = v.w;
        }
        unsigned t = d0 + d1 + d2 + d3;
        unsigned x = t;
        #pragma unroll
        for (int d = 1; d < 64; d <<= 1) {
            unsigned tt = __shfl_up(x, d, 64);
            if (lane >= d) x += tt;
        }
        if (lane == 63) wsum[wid] = x;
        __syncthreads();
        if (threadIdx.x == 0) {
            unsigned run = carry_s;
            #pragma unroll
            for (int w = 0; w < 16; ++w) { unsigned tmp = wsum[w]; wsum[w] = run; run += tmp; }
            carry_s = run;
        }
        __syncthreads();
        if (i0 < N_NODES) {
            unsigned b = wsum[wid] + (x - t);
            uint4 rp;
            rp.x = b; rp.y = b + d0; rp.z = b + d0 + d1; rp.w = b + d0 + d1 + d2;
            *(uint4*)(row_ptr + i0) = rp;
        }
        __syncthreads();
    }
    if (threadIdx.x == 0) row_ptr[N_NODES] = carry_s;
}

// ---------------------------------------------------------------------------
// Kernel 3 (pre2), fused by block range:
//   [0, 6250)       : atomic-free CSR fill via rank
//   [6250, 18750)   : featn = bf16(feat * norm_src), norm from partial sums
// ---------------------------------------------------------------------------
__global__ __launch_bounds__(256)
void pre2_kernel(const int* __restrict__ src, const int* __restrict__ dst,
                 const unsigned* __restrict__ row_ptr, const unsigned* __restrict__ rank,
                 unsigned* __restrict__ edge_src,
                 const float* __restrict__ feat, const unsigned* __restrict__ partial_out,
                 ushort* __restrict__ featn) {
    const int b = blockIdx.x;
    if (b < EDGE_BLOCKS) {
        int e = b * 256 + threadIdx.x;
        edge_src[row_ptr[dst[e]] + rank[e]] = (unsigned)src[e];
    } else {
        int id = (b - EDGE_BLOCKS) * 256 + threadIdx.x;   // exact N_NODES*32
        int row = id >> 5;
        unsigned d = partial_out[row] + partial_out[N_NODES + row]
                   + partial_out[2 * N_NODES + row] + partial_out[3 * N_NODES + row];
        float ns = rsqrtf(fmaxf((float)d, 1.f));
        float4 v = ((const float4*)feat)[id];
        ushort4 o;
        o.x = (ushort)f2bf(v.x * ns);
        o.y = (ushort)f2bf(v.y * ns);
        o.z = (ushort)f2bf(v.z * ns);
        o.w = (ushort)f2bf(v.w * ns);
        ((ushort4*)featn)[id] = o;
    }
}

// ---------------------------------------------------------------------------
// Kernel 4: row-per-wave gather SpMM over bf16 featn -> aggb (bf16)
// ---------------------------------------------------------------------------
__global__ __launch_bounds__(256)
void spmm_kernel(const ushort* __restrict__ featn,
                 const unsigned* __restrict__ row_ptr, const unsigned* __restrict__ edge_src,
                 unsigned* __restrict__ aggb_u32) {
    int gw = (blockIdx.x * 256 + threadIdx.x) >> 6;
    int lane = threadIdx.x & 63;
    if (gw >= N_NODES) return;
    unsigned beg = row_ptr[gw], end = row_ptr[gw + 1];
    float a0 = 0.f, a1 = 0.f;
    unsigned e = beg;
    for (; e + 4 <= end; e += 4) {
        unsigned s0 = edge_src[e + 0];
        unsigned s1 = edge_src[e + 1];
        unsigned s2 = edge_src[e + 2];
        unsigned s3 = edge_src[e + 3];
        unsigned v0 = *(const unsigned*)(featn + (size_t)s0 * IN_DIM + 2 * lane);
        unsigned v1 = *(const unsigned*)(featn + (size_t)s1 * IN_DIM + 2 * lane);
        unsigned v2 = *(const unsigned*)(featn + (size_t)s2 * IN_DIM + 2 * lane);
        unsigned v3 = *(const unsigned*)(featn + (size_t)s3 * IN_DIM + 2 * lane);
        a0 += __builtin_bit_cast(float, v0 << 16);
        a1 += __builtin_bit_cast(float, v0 & 0xffff0000u);
        a0 += __builtin_bit_cast(float, v1 << 16);
        a1 += __builtin_bit_cast(float, v1 & 0xffff0000u);
        a0 += __builtin_bit_cast(float, v2 << 16);
        a1 += __builtin_bit_cast(float, v2 & 0xffff0000u);
        a0 += __builtin_bit_cast(float, v3 << 16);
        a1 += __builtin_bit_cast(float, v3 & 0xffff0000u);
    }
    for (; e < end; ++e) {
        unsigned s = edge_src[e];
        unsigned v = *(const unsigned*)(featn + (size_t)s * IN_DIM + 2 * lane);
        a0 += __builtin_bit_cast(float, v << 16);
        a1 += __builtin_bit_cast(float, v & 0xffff0000u);
    }
    float nd = rsqrtf(fmaxf((float)(end - beg), 1.0f));
    unsigned lo = (unsigned)(ushort)f2bf(a0 * nd);
    unsigned hi = (unsigned)(ushort)f2bf(a1 * nd);
    aggb_u32[(size_t)gw * (IN_DIM / 2) + lane] = lo | (hi << 16);
}

// ---------------------------------------------------------------------------
// Kernel 5: GEMM1 + LN + ReLU -> lnb (bf16, MFMA C-fragment layout)
// 512 threads = 8 waves; B staged once in 64 KB LDS; barrier-free main loop.
// ---------------------------------------------------------------------------
__global__ __launch_bounds__(512, 2)
void gemm1_ln_kernel(const ushort* __restrict__ aggb, const ushort* __restrict__ Wfrag,
                     const float* __restrict__ bvec, const float* __restrict__ gamma,
                     const float* __restrict__ beta, ushort* __restrict__ lnb) {
    __shared__ __align__(16) ushort Blds[32768];   // 64 KB
    const int tid = threadIdx.x;
    #pragma unroll
    for (int i = 0; i < 8; ++i)
        ((uint4*)Blds)[tid + i * 512] = ((const uint4*)Wfrag)[tid + i * 512];
    __syncthreads();

    const int lane = tid & 63;
    const int c = lane & 15, g = lane >> 4;
    const int gw = blockIdx.x * 8 + (tid >> 6);

    float bb[16], ga[16], be[16];
    #pragma unroll
    for (int n = 0; n < 16; ++n) {
        bb[n] = bvec[n * 16 + c];
        ga[n] = gamma[n * 16 + c];
        be[n] = beta[n * 16 + c];
    }

    for (int t = gw; t < NT; t += 4096) {
        const int r0 = t * 16;
        bf16x8 A[4];
        #pragma unroll
        for (int ks = 0; ks < 4; ++ks)
            A[ks] = *(const bf16x8*)(aggb + (size_t)(r0 + c) * IN_DIM + ks * 32 + g * 8);

        f32x4 acc[16];
        #pragma unroll
        for (int n = 0; n < 16; ++n) {
            acc[n] = (f32x4){bb[n], bb[n], bb[n], bb[n]};
            #pragma unroll
            for (int ks = 0; ks < 4; ++ks) {
                bf16x8 b = *(const bf16x8*)(Blds + ((n * 4 + ks) * 64 + lane) * 8);
                acc[n] = __builtin_amdgcn_mfma_f32_16x16x32_bf16(A[ks], b, acc[n], 0, 0, 0);
            }
        }

        float s1[4], s2[4];
        #pragma unroll
        for (int j = 0; j < 4; ++j) { s1[j] = 0.f; s2[j] = 0.f; }
        #pragma unroll
        for (int n = 0; n < 16; ++n) {
            #pragma unroll
            for (int j = 0; j < 4; ++j) {
                s1[j] += acc[n][j];
                s2[j] = fmaf(acc[n][j], acc[n][j], s2[j]);
            }
        }
        #pragma unroll
        for (int m = 1; m <= 8; m <<= 1) {
            #pragma unroll
            for (int j = 0; j < 4; ++j) {
                s1[j] += __shfl_xor(s1[j], m, 64);
                s2[j] += __shfl_xor(s2[j], m, 64);
            }
        }
        float mu[4], rstd[4];
        #pragma unroll
        for (int j = 0; j < 4; ++j) {
            mu[j] = s1[j] * (1.f / HID_DIM);
            float var = s2[j] * (1.f / HID_DIM) - mu[j] * mu[j];
            rstd[j] = rsqrtf(var + LN_EPS);
        }

        #pragma unroll
        for (int n = 0; n < 16; ++n) {
            ushort4 o;
            o.x = (ushort)f2bf(fmaxf(fmaf((acc[n][0] - mu[0]) * rstd[0], ga[n], be[n]), 0.f));
            o.y = (ushort)f2bf(fmaxf(fmaf((acc[n][1] - mu[1]) * rstd[1], ga[n], be[n]), 0.f));
            o.z = (ushort)f2bf(fmaxf(fmaf((acc[n][2] - mu[2]) * rstd[2], ga[n], be[n]), 0.f));
            o.w = (ushort)f2bf(fmaxf(fmaf((acc[n][3] - mu[3]) * rstd[3], ga[n], be[n]), 0.f));
            *(ushort4*)(lnb + ((size_t)(t * 16 + n) * 64 + lane) * 4) = o;
        }
    }
}

// ---------------------------------------------------------------------------
// Kernel 6: GEMM2 (feat @ skipW) + lnb + skip_b -> out (f32 row-major)
// ---------------------------------------------------------------------------
__global__ __launch_bounds__(512, 2)
void gemm2_kernel(const ushort* __restrict__ lnb, const float* __restrict__ feat,
                  const ushort* __restrict__ sWfrag, const float* __restrict__ skipb,
                  float* __restrict__ out) {
    __shared__ __align__(16) ushort Blds[32768];   // 64 KB
    const int tid = threadIdx.x;
    #pragma unroll
    for (int i = 0; i < 8; ++i)
        ((uint4*)Blds)[tid + i * 512] = ((const uint4*)sWfrag)[tid + i * 512];
    __syncthreads();

    const int lane = tid & 63;
    const int c = lane & 15, g = lane >> 4;
    const int gw = blockIdx.x * 8 + (tid >> 6);

    float sb[16];
    #pragma unroll
    for (int n = 0; n < 16; ++n) sb[n] = skipb[n * 16 + c];

    for (int t = gw; t < NT; t += 4096) {
        const int r0 = t * 16;
        bf16x8 A[4];
        #pragma unroll
        for (int ks = 0; ks < 4; ++ks) {
            const float* fp = feat + (size_t)(r0 + c) * IN_DIM + ks * 32 + g * 8;
            float4 u = *(const float4*)fp;
            float4 v = *(const float4*)(fp + 4);
            bf16x8 a;
            a[0] = f2bf(u.x); a[1] = f2bf(u.y); a[2] = f2bf(u.z); a[3] = f2bf(u.w);
            a[4] = f2bf(v.x); a[5] = f2bf(v.y); a[6] = f2bf(v.z); a[7] = f2bf(v.w);
            A[ks] = a;
        }

        f32x4 acc[16];
        #pragma unroll
        for (int n = 0; n < 16; ++n) {
            ushort4 l = *(const ushort4*)(lnb + ((size_t)(t * 16 + n) * 64 + lane) * 4);
            acc[n] = (f32x4){bf2f(l.x), bf2f(l.y), bf2f(l.z), bf2f(l.w)};
            #pragma unroll
            for (int ks = 0; ks < 4; ++ks) {
                bf16x8 b = *(const bf16x8*)(Blds + ((n * 4 + ks) * 64 + lane) * 8);
                acc[n] = __builtin_amdgcn_mfma_f32_16x16x32_bf16(A[ks], b, acc[n], 0, 0, 0);
            }
        }

        #pragma unroll
        for (int n = 0; n < 16; ++n) {
            #pragma unroll
            for (int j = 0; j < 4; ++j)
                out[(size_t)(r0 + g * 4 + j) * HID_DIM + n * 16 + c] = acc[n][j] + sb[n];
        }
    }
}

// ---------------------------------------------------------------------------
extern "C" void kernel_launch(void* const* d_in, const int* in_sizes, int n_in,
                              void* d_out, int out_size, void* d_ws, size_t ws_size,
                              hipStream_t stream) {
    const float* feat  = (const float*)d_in[0];
    const int*   src   = (const int*)d_in[1];
    const int*   dst   = (const int*)d_in[2];
    const float* W     = (const float*)d_in[3];
    const float* bvec  = (const float*)d_in[4];
    const float* gamma = (const float*)d_in[5];
    const float* beta  = (const float*)d_in[6];
    const float* skipW = (const float*)d_in[7];
    const float* skipb = (const float*)d_in[8];
    float* out = (float*)d_out;

    // workspace, peak ≈ 77 MB (same as last round):
    // [Wfrag 64K][sWfrag 64K][aggb 25.6M][xbase: featn 25.6 | edge_src 6.4 |
    //  rank 6.4 | partial_out 1.6 | deg_in .4 | row_ptr .4]
    // lnb (51.2M bf16 C-frag) aliases xbase — every xbase member is dead
    // before gemm1 writes lnb.
    char* ws = (char*)d_ws;
    ushort*   Wfrag       = (ushort*)ws;                               // 64 KB
    ushort*   sWfrag      = Wfrag + 32768;                             // 64 KB
    ushort*   aggb        = sWfrag + 32768;                            // 25.6 MB
    char*     xbase       = (char*)(aggb + (size_t)N_NODES * IN_DIM);
    ushort*   featn       = (ushort*)xbase;                            // 25.6 MB
    unsigned* edge_src    = (unsigned*)(featn + (size_t)N_NODES * IN_DIM); // 6.4 MB
    unsigned* rank        = edge_src + N_EDGES;                        // 6.4 MB
    unsigned* partial_out = rank + N_EDGES;                            // 1.6 MB
    unsigned* deg_in      = partial_out + 4 * N_NODES;                 // 400 KB
    unsigned* row_ptr     = deg_in + N_NODES;                          // 400 KB
    ushort*   lnb         = (ushort*)xbase;                            // 51.2 MB alias

    hipMemsetAsync(deg_in, 0, (size_t)N_NODES * 4, stream);

    pre1_kernel<<<HIST_BLOCKS + WCVT_BLOCKS + EDGE_BLOCKS, 256, 0, stream>>>(
        src, dst, deg_in, rank, partial_out, W, skipW, Wfrag, sWfrag);

    scan_kernel<<<1, 1024, 0, stream>>>(deg_in, row_ptr);

    pre2_kernel<<<EDGE_BLOCKS + FCVT_BLOCKS, 256, 0, stream>>>(
        src, dst, row_ptr, rank, edge_src, feat, partial_out, featn);

    spmm_kernel<<<(N_NODES * 64 + 255) / 256, 256, 0, stream>>>(featn, row_ptr, edge_src,
                                                                (unsigned*)aggb);

    gemm1_ln_kernel<<<512, 512, 0, stream>>>(aggb, Wfrag, bvec, gamma, beta, lnb);

    gemm2_kernel<<<512, 512, 0, stream>>>(lnb, feat, sWfrag, skipb, out);
}

// Round 8
// 486.042 us; speedup vs baseline: 1.2546x; 1.2546x over previous
//
#include <hip/hip_runtime.h>
#include <hip/hip_bf16.h>

#define N_NODES 100000
#define N_EDGES 1600000
#define IN_DIM 128
#define HID_DIM 256
#define LN_EPS 1e-5f
#define NT (N_NODES / 16)   // 6250 16-row tiles, exact

#define EDGE_BLOCKS (N_EDGES / 256)       // 6250, exact
#define FCVT_BLOCKS (N_NODES * 32 / 256)  // 12500, exact

typedef short bf16x8 __attribute__((ext_vector_type(8)));
typedef float f32x4  __attribute__((ext_vector_type(4)));

static __device__ __forceinline__ short f2bf(float x) {
    return __builtin_bit_cast(short, __float2bfloat16(x));  // RNE round
}
static __device__ __forceinline__ float bf2f(ushort u) {
    return __builtin_bit_cast(float, ((unsigned)u) << 16);
}

// ---------------------------------------------------------------------------
// Kernel 1: degree counts + CSR rank (atomic return value).
// 3.2M device-scope atomics is the irreducible cost (32 B memory-side txn
// each, ~25 G/s); rank costs one extra coalesced 4 B store per edge and
// makes the CSR fill atomic-free.
// ---------------------------------------------------------------------------
__global__ __launch_bounds__(256)
void deg_rank_kernel(const int* __restrict__ src, const int* __restrict__ dst,
                     unsigned* __restrict__ deg_out, unsigned* __restrict__ deg_in,
                     unsigned* __restrict__ rank) {
    int e = blockIdx.x * 256 + threadIdx.x;   // grid is exact
    atomicAdd(&deg_out[src[e]], 1u);
    rank[e] = atomicAdd(&deg_in[dst[e]], 1u);
}

// ---------------------------------------------------------------------------
// Kernel 2: W / skipW -> bf16 in MFMA B-fragment-major order
// ---------------------------------------------------------------------------
__global__ void wcvt_kernel(const float* __restrict__ W, const float* __restrict__ sW,
                            ushort* __restrict__ Wfrag, ushort* __restrict__ sWfrag) {
    int tid = blockIdx.x * blockDim.x + threadIdx.x;
    if (tid >= 8192) return;
    const float* srcm = (tid < 4096) ? W : sW;
    ushort* dstm = (tid < 4096) ? Wfrag : sWfrag;
    int u = tid & 4095;
    int lane = u & 63;
    int ks = (u >> 6) & 3;
    int n = u >> 8;
    int c = lane & 15, g = lane >> 4;
    int col = n * 16 + c;
    int k0 = ks * 32 + g * 8;
    ushort4 lo, hi;
    lo.x = (ushort)f2bf(srcm[(size_t)(k0 + 0) * HID_DIM + col]);
    lo.y = (ushort)f2bf(srcm[(size_t)(k0 + 1) * HID_DIM + col]);
    lo.z = (ushort)f2bf(srcm[(size_t)(k0 + 2) * HID_DIM + col]);
    lo.w = (ushort)f2bf(srcm[(size_t)(k0 + 3) * HID_DIM + col]);
    hi.x = (ushort)f2bf(srcm[(size_t)(k0 + 4) * HID_DIM + col]);
    hi.y = (ushort)f2bf(srcm[(size_t)(k0 + 5) * HID_DIM + col]);
    hi.z = (ushort)f2bf(srcm[(size_t)(k0 + 6) * HID_DIM + col]);
    hi.w = (ushort)f2bf(srcm[(size_t)(k0 + 7) * HID_DIM + col]);
    *(ushort4*)(dstm + (size_t)u * 8)     = lo;
    *(ushort4*)(dstm + (size_t)u * 8 + 4) = hi;
}

// ---------------------------------------------------------------------------
// Kernel 3: single-block exclusive scan (4 elems/thread) deg_in -> row_ptr
// ---------------------------------------------------------------------------
__global__ __launch_bounds__(1024)
void scan_kernel(const unsigned* __restrict__ deg_in, unsigned* __restrict__ row_ptr) {
    __shared__ unsigned wsum[16];
    __shared__ unsigned carry_s;
    if (threadIdx.x == 0) carry_s = 0;
    __syncthreads();
    const int lane = threadIdx.x & 63;
    const int wid  = threadIdx.x >> 6;
    for (int base = 0; base < N_NODES; base += 4096) {
        int i0 = base + threadIdx.x * 4;
        unsigned d0 = 0, d1 = 0, d2 = 0, d3 = 0;
        if (i0 < N_NODES) {
            uint4 v = *(const uint4*)(deg_in + i0);
            d0 = v.x; d1 = v.y; d2 = v.z; d3 = v.w;
        }
        unsigned t = d0 + d1 + d2 + d3;
        unsigned x = t;
        #pragma unroll
        for (int d = 1; d < 64; d <<= 1) {
            unsigned tt = __shfl_up(x, d, 64);
            if (lane >= d) x += tt;
        }
        if (lane == 63) wsum[wid] = x;
        __syncthreads();
        if (threadIdx.x == 0) {
            unsigned run = carry_s;
            #pragma unroll
            for (int w = 0; w < 16; ++w) { unsigned tmp = wsum[w]; wsum[w] = run; run += tmp; }
            carry_s = run;
        }
        __syncthreads();
        if (i0 < N_NODES) {
            unsigned b = wsum[wid] + (x - t);
            uint4 rp;
            rp.x = b; rp.y = b + d0; rp.z = b + d0 + d1; rp.w = b + d0 + d1 + d2;
            *(uint4*)(row_ptr + i0) = rp;
        }
        __syncthreads();
    }
    if (threadIdx.x == 0) row_ptr[N_NODES] = carry_s;
}

// ---------------------------------------------------------------------------
// Kernel 4 (pre2), fused by block range:
//   [0, 6250)       : atomic-free CSR fill via rank
//   [6250, 18750)   : featn = bf16(feat * norm_src)
// ---------------------------------------------------------------------------
__global__ __launch_bounds__(256)
void pre2_kernel(const int* __restrict__ src, const int* __restrict__ dst,
                 const unsigned* __restrict__ row_ptr, const unsigned* __restrict__ rank,
                 unsigned* __restrict__ edge_src,
                 const float* __restrict__ feat, const unsigned* __restrict__ deg_out,
                 ushort* __restrict__ featn) {
    const int b = blockIdx.x;
    if (b < EDGE_BLOCKS) {
        int e = b * 256 + threadIdx.x;
        edge_src[row_ptr[dst[e]] + rank[e]] = (unsigned)src[e];
    } else {
        int id = (b - EDGE_BLOCKS) * 256 + threadIdx.x;   // exact N_NODES*32
        int row = id >> 5;
        float ns = rsqrtf(fmaxf((float)deg_out[row], 1.f));
        float4 v = ((const float4*)feat)[id];
        ushort4 o;
        o.x = (ushort)f2bf(v.x * ns);
        o.y = (ushort)f2bf(v.y * ns);
        o.z = (ushort)f2bf(v.z * ns);
        o.w = (ushort)f2bf(v.w * ns);
        ((ushort4*)featn)[id] = o;
    }
}

// ---------------------------------------------------------------------------
// Kernel 5: row-per-wave gather SpMM over bf16 featn -> aggb (bf16)
// ---------------------------------------------------------------------------
__global__ __launch_bounds__(256)
void spmm_kernel(const ushort* __restrict__ featn,
                 const unsigned* __restrict__ row_ptr, const unsigned* __restrict__ edge_src,
                 unsigned* __restrict__ aggb_u32) {
    int gw = (blockIdx.x * 256 + threadIdx.x) >> 6;
    int lane = threadIdx.x & 63;
    if (gw >= N_NODES) return;
    unsigned beg = row_ptr[gw], end = row_ptr[gw + 1];
    float a0 = 0.f, a1 = 0.f;
    unsigned e = beg;
    for (; e + 4 <= end; e += 4) {
        unsigned s0 = edge_src[e + 0];
        unsigned s1 = edge_src[e + 1];
        unsigned s2 = edge_src[e + 2];
        unsigned s3 = edge_src[e + 3];
        unsigned v0 = *(const unsigned*)(featn + (size_t)s0 * IN_DIM + 2 * lane);
        unsigned v1 = *(const unsigned*)(featn + (size_t)s1 * IN_DIM + 2 * lane);
        unsigned v2 = *(const unsigned*)(featn + (size_t)s2 * IN_DIM + 2 * lane);
        unsigned v3 = *(const unsigned*)(featn + (size_t)s3 * IN_DIM + 2 * lane);
        a0 += __builtin_bit_cast(float, v0 << 16);
        a1 += __builtin_bit_cast(float, v0 & 0xffff0000u);
        a0 += __builtin_bit_cast(float, v1 << 16);
        a1 += __builtin_bit_cast(float, v1 & 0xffff0000u);
        a0 += __builtin_bit_cast(float, v2 << 16);
        a1 += __builtin_bit_cast(float, v2 & 0xffff0000u);
        a0 += __builtin_bit_cast(float, v3 << 16);
        a1 += __builtin_bit_cast(float, v3 & 0xffff0000u);
    }
    for (; e < end; ++e) {
        unsigned s = edge_src[e];
        unsigned v = *(const unsigned*)(featn + (size_t)s * IN_DIM + 2 * lane);
        a0 += __builtin_bit_cast(float, v << 16);
        a1 += __builtin_bit_cast(float, v & 0xffff0000u);
    }
    float nd = rsqrtf(fmaxf((float)(end - beg), 1.0f));
    unsigned lo = (unsigned)(ushort)f2bf(a0 * nd);
    unsigned hi = (unsigned)(ushort)f2bf(a1 * nd);
    aggb_u32[(size_t)gw * (IN_DIM / 2) + lane] = lo | (hi << 16);
}

// ---------------------------------------------------------------------------
// Kernel 6: GEMM1 + LN + ReLU -> lnb (bf16, MFMA C-fragment layout)
// 512 threads = 8 waves; B staged once in 64 KB LDS; barrier-free main loop.
// ---------------------------------------------------------------------------
__global__ __launch_bounds__(512, 2)
void gemm1_ln_kernel(const ushort* __restrict__ aggb, const ushort* __restrict__ Wfrag,
                     const float* __restrict__ bvec, const float* __restrict__ gamma,
                     const float* __restrict__ beta, ushort* __restrict__ lnb) {
    __shared__ __align__(16) ushort Blds[32768];   // 64 KB
    const int tid = threadIdx.x;
    #pragma unroll
    for (int i = 0; i < 8; ++i)
        ((uint4*)Blds)[tid + i * 512] = ((const uint4*)Wfrag)[tid + i * 512];
    __syncthreads();

    const int lane = tid & 63;
    const int c = lane & 15, g = lane >> 4;
    const int gw = blockIdx.x * 8 + (tid >> 6);

    float bb[16], ga[16], be[16];
    #pragma unroll
    for (int n = 0; n < 16; ++n) {
        bb[n] = bvec[n * 16 + c];
        ga[n] = gamma[n * 16 + c];
        be[n] = beta[n * 16 + c];
    }

    for (int t = gw; t < NT; t += 4096) {
        const int r0 = t * 16;
        bf16x8 A[4];
        #pragma unroll
        for (int ks = 0; ks < 4; ++ks)
            A[ks] = *(const bf16x8*)(aggb + (size_t)(r0 + c) * IN_DIM + ks * 32 + g * 8);

        f32x4 acc[16];
        #pragma unroll
        for (int n = 0; n < 16; ++n) {
            acc[n] = (f32x4){bb[n], bb[n], bb[n], bb[n]};
            #pragma unroll
            for (int ks = 0; ks < 4; ++ks) {
                bf16x8 b = *(const bf16x8*)(Blds + ((n * 4 + ks) * 64 + lane) * 8);
                acc[n] = __builtin_amdgcn_mfma_f32_16x16x32_bf16(A[ks], b, acc[n], 0, 0, 0);
            }
        }

        float s1[4], s2[4];
        #pragma unroll
        for (int j = 0; j < 4; ++j) { s1[j] = 0.f; s2[j] = 0.f; }
        #pragma unroll
        for (int n = 0; n < 16; ++n) {
            #pragma unroll
            for (int j = 0; j < 4; ++j) {
                s1[j] += acc[n][j];
                s2[j] = fmaf(acc[n][j], acc[n][j], s2[j]);
            }
        }
        #pragma unroll
        for (int m = 1; m <= 8; m <<= 1) {
            #pragma unroll
            for (int j = 0; j < 4; ++j) {
                s1[j] += __shfl_xor(s1[j], m, 64);
                s2[j] += __shfl_xor(s2[j], m, 64);
            }
        }
        float mu[4], rstd[4];
        #pragma unroll
        for (int j = 0; j < 4; ++j) {
            mu[j] = s1[j] * (1.f / HID_DIM);
            float var = s2[j] * (1.f / HID_DIM) - mu[j] * mu[j];
            rstd[j] = rsqrtf(var + LN_EPS);
        }

        #pragma unroll
        for (int n = 0; n < 16; ++n) {
            ushort4 o;
            o.x = (ushort)f2bf(fmaxf(fmaf((acc[n][0] - mu[0]) * rstd[0], ga[n], be[n]), 0.f));
            o.y = (ushort)f2bf(fmaxf(fmaf((acc[n][1] - mu[1]) * rstd[1], ga[n], be[n]), 0.f));
            o.z = (ushort)f2bf(fmaxf(fmaf((acc[n][2] - mu[2]) * rstd[2], ga[n], be[n]), 0.f));
            o.w = (ushort)f2bf(fmaxf(fmaf((acc[n][3] - mu[3]) * rstd[3], ga[n], be[n]), 0.f));
            *(ushort4*)(lnb + ((size_t)(t * 16 + n) * 64 + lane) * 4) = o;
        }
    }
}

// ---------------------------------------------------------------------------
// Kernel 7: GEMM2 (feat @ skipW) + lnb + skip_b -> out (f32 row-major)
// ---------------------------------------------------------------------------
__global__ __launch_bounds__(512, 2)
void gemm2_kernel(const ushort* __restrict__ lnb, const float* __restrict__ feat,
                  const ushort* __restrict__ sWfrag, const float* __restrict__ skipb,
                  float* __restrict__ out) {
    __shared__ __align__(16) ushort Blds[32768];   // 64 KB
    const int tid = threadIdx.x;
    #pragma unroll
    for (int i = 0; i < 8; ++i)
        ((uint4*)Blds)[tid + i * 512] = ((const uint4*)sWfrag)[tid + i * 512];
    __syncthreads();

    const int lane = tid & 63;
    const int c = lane & 15, g = lane >> 4;
    const int gw = blockIdx.x * 8 + (tid >> 6);

    float sb[16];
    #pragma unroll
    for (int n = 0; n < 16; ++n) sb[n] = skipb[n * 16 + c];

    for (int t = gw; t < NT; t += 4096) {
        const int r0 = t * 16;
        bf16x8 A[4];
        #pragma unroll
        for (int ks = 0; ks < 4; ++ks) {
            const float* fp = feat + (size_t)(r0 + c) * IN_DIM + ks * 32 + g * 8;
            float4 u = *(const float4*)fp;
            float4 v = *(const float4*)(fp + 4);
            bf16x8 a;
            a[0] = f2bf(u.x); a[1] = f2bf(u.y); a[2] = f2bf(u.z); a[3] = f2bf(u.w);
            a[4] = f2bf(v.x); a[5] = f2bf(v.y); a[6] = f2bf(v.z); a[7] = f2bf(v.w);
            A[ks] = a;
        }

        f32x4 acc[16];
        #pragma unroll
        for (int n = 0; n < 16; ++n) {
            ushort4 l = *(const ushort4*)(lnb + ((size_t)(t * 16 + n) * 64 + lane) * 4);
            acc[n] = (f32x4){bf2f(l.x), bf2f(l.y), bf2f(l.z), bf2f(l.w)};
            #pragma unroll
            for (int ks = 0; ks < 4; ++ks) {
                bf16x8 b = *(const bf16x8*)(Blds + ((n * 4 + ks) * 64 + lane) * 8);
                acc[n] = __builtin_amdgcn_mfma_f32_16x16x32_bf16(A[ks], b, acc[n], 0, 0, 0);
            }
        }

        #pragma unroll
        for (int n = 0; n < 16; ++n) {
            #pragma unroll
            for (int j = 0; j < 4; ++j)
                out[(size_t)(r0 + g * 4 + j) * HID_DIM + n * 16 + c] = acc[n][j] + sb[n];
        }
    }
}

// ---------------------------------------------------------------------------
extern "C" void kernel_launch(void* const* d_in, const int* in_sizes, int n_in,
                              void* d_out, int out_size, void* d_ws, size_t ws_size,
                              hipStream_t stream) {
    const float* feat  = (const float*)d_in[0];
    const int*   src   = (const int*)d_in[1];
    const int*   dst   = (const int*)d_in[2];
    const float* W     = (const float*)d_in[3];
    const float* bvec  = (const float*)d_in[4];
    const float* gamma = (const float*)d_in[5];
    const float* beta  = (const float*)d_in[6];
    const float* skipW = (const float*)d_in[7];
    const float* skipb = (const float*)d_in[8];
    float* out = (float*)d_out;

    // workspace, peak ≈ 66 MB:
    // [Wfrag 64K][sWfrag 64K][aggb 25.6M][xbase: featn 25.6 | edge_src 6.4 |
    //  rank 6.4 | deg_out .4 | deg_in .4 | row_ptr .4]
    // lnb (51.2M bf16 C-frag) aliases xbase — every xbase member is dead
    // before gemm1 writes lnb.
    char* ws = (char*)d_ws;
    ushort*   Wfrag    = (ushort*)ws;                               // 64 KB
    ushort*   sWfrag   = Wfrag + 32768;                             // 64 KB
    ushort*   aggb     = sWfrag + 32768;                            // 25.6 MB
    char*     xbase    = (char*)(aggb + (size_t)N_NODES * IN_DIM);
    ushort*   featn    = (ushort*)xbase;                            // 25.6 MB
    unsigned* edge_src = (unsigned*)(featn + (size_t)N_NODES * IN_DIM); // 6.4 MB
    unsigned* rank     = edge_src + N_EDGES;                        // 6.4 MB
    unsigned* deg_out  = rank + N_EDGES;                            // 400 KB
    unsigned* deg_in   = deg_out + N_NODES;                         // 400 KB
    unsigned* row_ptr  = deg_in + N_NODES;                          // 400 KB + pad
    ushort*   lnb      = (ushort*)xbase;                            // 51.2 MB alias

    hipMemsetAsync(deg_out, 0, (size_t)2 * N_NODES * 4, stream);

    wcvt_kernel<<<32, 256, 0, stream>>>(W, skipW, Wfrag, sWfrag);

    deg_rank_kernel<<<EDGE_BLOCKS, 256, 0, stream>>>(src, dst, deg_out, deg_in, rank);

    scan_kernel<<<1, 1024, 0, stream>>>(deg_in, row_ptr);

    pre2_kernel<<<EDGE_BLOCKS + FCVT_BLOCKS, 256, 0, stream>>>(
        src, dst, row_ptr, rank, edge_src, feat, deg_out, featn);

    spmm_kernel<<<(N_NODES * 64 + 255) / 256, 256, 0, stream>>>(featn, row_ptr, edge_src,
                                                                (unsigned*)aggb);

    gemm1_ln_kernel<<<512, 512, 0, stream>>>(aggb, Wfrag, bvec, gamma, beta, lnb);

    gemm2_kernel<<<512, 512, 0, stream>>>(lnb, feat, sWfrag, skipb, out);
}

// Round 9
// 391.816 us; speedup vs baseline: 1.5564x; 1.2405x over previous
//
#include <hip/hip_runtime.h>
#include <hip/hip_bf16.h>

#define N_NODES 100000
#define N_EDGES 1600000
#define IN_DIM 128
#define HID_DIM 256
#define LN_EPS 1e-5f
#define NT (N_NODES / 16)   // 6250 16-row tiles, exact

// histogram geometry
#define NCHUNK 32
#define CHUNK_E (N_EDGES / NCHUNK)     // 50000 edges/chunk (12500 int4, exact)
#define NSLICE 8
#define SLICE (N_NODES / NSLICE)       // 12500 nodes/slice (50 KB LDS bins)
#define HBLK (NCHUNK * NSLICE)         // 256 blocks per histogrammed array

#define EDGE_BLOCKS (N_EDGES / 256)       // 6250, exact
#define FCVT_BLOCKS (N_NODES * 32 / 256)  // 12500, exact

typedef short bf16x8 __attribute__((ext_vector_type(8)));
typedef float f32x4  __attribute__((ext_vector_type(4)));

static __device__ __forceinline__ short f2bf(float x) {
    return __builtin_bit_cast(short, __float2bfloat16(x));  // RNE round
}
static __device__ __forceinline__ float bf2f(ushort u) {
    return __builtin_bit_cast(float, ((unsigned)u) << 16);
}

// ---------------------------------------------------------------------------
// Kernel 1: LDS-bin histograms — NO global atomics.
//   blocks [0, 256)   : histogram of src  -> p_out[chunk][node]
//   blocks [256, 512) : histogram of dst  -> p_in[chunk][node], and the LDS
//                       atomic's return value = within-chunk rank -> rank16[e]
// 1024 threads (16 waves = 4/SIMD for latency hiding); each block scans one
// 50k-edge chunk and keeps one 12.5k-node slice in LDS.
// ---------------------------------------------------------------------------
__global__ __launch_bounds__(1024)
void hist_kernel(const int* __restrict__ src, const int* __restrict__ dst,
                 unsigned* __restrict__ p_out, unsigned* __restrict__ p_in,
                 ushort* __restrict__ rank16) {
    __shared__ unsigned bins[SLICE];   // 50 KB
    const int b = blockIdx.x;
    const bool isdst = (b >= HBLK);
    const int bb = isdst ? (b - HBLK) : b;
    const int ci = bb >> 3;            // chunk 0..31
    const int si = bb & 7;             // slice 0..7
    const int s0 = si * SLICE;

    for (int i = threadIdx.x; i < SLICE; i += 1024) bins[i] = 0;
    __syncthreads();

    const int4* ep4 = (const int4*)((isdst ? dst : src) + ci * CHUNK_E);
    if (isdst) {
        const int ebase = ci * CHUNK_E;
        for (int i = threadIdx.x; i < CHUNK_E / 4; i += 1024) {
            int4 v = ep4[i];
            int e0 = ebase + i * 4;
            unsigned u0 = (unsigned)(v.x - s0);
            unsigned u1 = (unsigned)(v.y - s0);
            unsigned u2 = (unsigned)(v.z - s0);
            unsigned u3 = (unsigned)(v.w - s0);
            if (u0 < SLICE) rank16[e0 + 0] = (ushort)atomicAdd(&bins[u0], 1u);
            if (u1 < SLICE) rank16[e0 + 1] = (ushort)atomicAdd(&bins[u1], 1u);
            if (u2 < SLICE) rank16[e0 + 2] = (ushort)atomicAdd(&bins[u2], 1u);
            if (u3 < SLICE) rank16[e0 + 3] = (ushort)atomicAdd(&bins[u3], 1u);
        }
    } else {
        for (int i = threadIdx.x; i < CHUNK_E / 4; i += 1024) {
            int4 v = ep4[i];
            unsigned u0 = (unsigned)(v.x - s0);
            unsigned u1 = (unsigned)(v.y - s0);
            unsigned u2 = (unsigned)(v.z - s0);
            unsigned u3 = (unsigned)(v.w - s0);
            if (u0 < SLICE) atomicAdd(&bins[u0], 1u);
            if (u1 < SLICE) atomicAdd(&bins[u1], 1u);
            if (u2 < SLICE) atomicAdd(&bins[u2], 1u);
            if (u3 < SLICE) atomicAdd(&bins[u3], 1u);
        }
    }
    __syncthreads();

    unsigned* pp = (isdst ? p_in : p_out) + (size_t)ci * N_NODES + s0;
    for (int i = threadIdx.x; i < SLICE; i += 1024) pp[i] = bins[i];
}

// ---------------------------------------------------------------------------
// Kernel 2: per-node reduction: deg_out = sum(p_out); exclusive prefix of
// p_in over chunks (in place) -> deg_in.
// ---------------------------------------------------------------------------
__global__ __launch_bounds__(256)
void prefix_kernel(const unsigned* __restrict__ p_out, unsigned* __restrict__ p_in,
                   unsigned* __restrict__ deg_out, unsigned* __restrict__ deg_in) {
    int n = blockIdx.x * 256 + threadIdx.x;
    if (n >= N_NODES) return;
    unsigned so = 0;
    #pragma unroll
    for (int c = 0; c < NCHUNK; ++c) so += p_out[(size_t)c * N_NODES + n];
    deg_out[n] = so;
    unsigned run = 0;
    #pragma unroll
    for (int c = 0; c < NCHUNK; ++c) {
        unsigned t = p_in[(size_t)c * N_NODES + n];
        p_in[(size_t)c * N_NODES + n] = run;
        run += t;
    }
    deg_in[n] = run;
}

// ---------------------------------------------------------------------------
// Kernel 3: W / skipW -> bf16 in MFMA B-fragment-major order
// ---------------------------------------------------------------------------
__global__ void wcvt_kernel(const float* __restrict__ W, const float* __restrict__ sW,
                            ushort* __restrict__ Wfrag, ushort* __restrict__ sWfrag) {
    int tid = blockIdx.x * blockDim.x + threadIdx.x;
    if (tid >= 8192) return;
    const float* srcm = (tid < 4096) ? W : sW;
    ushort* dstm = (tid < 4096) ? Wfrag : sWfrag;
    int u = tid & 4095;
    int lane = u & 63;
    int ks = (u >> 6) & 3;
    int n = u >> 8;
    int c = lane & 15, g = lane >> 4;
    int col = n * 16 + c;
    int k0 = ks * 32 + g * 8;
    ushort4 lo, hi;
    lo.x = (ushort)f2bf(srcm[(size_t)(k0 + 0) * HID_DIM + col]);
    lo.y = (ushort)f2bf(srcm[(size_t)(k0 + 1) * HID_DIM + col]);
    lo.z = (ushort)f2bf(srcm[(size_t)(k0 + 2) * HID_DIM + col]);
    lo.w = (ushort)f2bf(srcm[(size_t)(k0 + 3) * HID_DIM + col]);
    hi.x = (ushort)f2bf(srcm[(size_t)(k0 + 4) * HID_DIM + col]);
    hi.y = (ushort)f2bf(srcm[(size_t)(k0 + 5) * HID_DIM + col]);
    hi.z = (ushort)f2bf(srcm[(size_t)(k0 + 6) * HID_DIM + col]);
    hi.w = (ushort)f2bf(srcm[(size_t)(k0 + 7) * HID_DIM + col]);
    *(ushort4*)(dstm + (size_t)u * 8)     = lo;
    *(ushort4*)(dstm + (size_t)u * 8 + 4) = hi;
}

// ---------------------------------------------------------------------------
// Kernel 4: single-block exclusive scan (4 elems/thread) deg_in -> row_ptr
// ---------------------------------------------------------------------------
__global__ __launch_bounds__(1024)
void scan_kernel(const unsigned* __restrict__ deg_in, unsigned* __restrict__ row_ptr) {
    __shared__ unsigned wsum[16];
    __shared__ unsigned carry_s;
    if (threadIdx.x == 0) carry_s = 0;
    __syncthreads();
    const int lane = threadIdx.x & 63;
    const int wid  = threadIdx.x >> 6;
    for (int base = 0; base < N_NODES; base += 4096) {
        int i0 = base + threadIdx.x * 4;
        unsigned d0 = 0, d1 = 0, d2 = 0, d3 = 0;
        if (i0 < N_NODES) {
            uint4 v = *(const uint4*)(deg_in + i0);
            d0 = v.x; d1 = v.y; d2 = v.z; d3 = v.w;
        }
        unsigned t = d0 + d1 + d2 + d3;
        unsigned x = t;
        #pragma unroll
        for (int d = 1; d < 64; d <<= 1) {
            unsigned tt = __shfl_up(x, d, 64);
            if (lane >= d) x += tt;
        }
        if (lane == 63) wsum[wid] = x;
        __syncthreads();
        if (threadIdx.x == 0) {
            unsigned run = carry_s;
            #pragma unroll
            for (int w = 0; w < 16; ++w) { unsigned tmp = wsum[w]; wsum[w] = run; run += tmp; }
            carry_s = run;
        }
        __syncthreads();
        if (i0 < N_NODES) {
            unsigned b = wsum[wid] + (x - t);
            uint4 rp;
            rp.x = b; rp.y = b + d0; rp.z = b + d0 + d1; rp.w = b + d0 + d1 + d2;
            *(uint4*)(row_ptr + i0) = rp;
        }
        __syncthreads();
    }
    if (threadIdx.x == 0) row_ptr[N_NODES] = carry_s;
}

// ---------------------------------------------------------------------------
// Kernel 5 (pre2), fused by block range:
//   [0, 6250)       : atomic-free CSR fill via chunk-prefix + within-chunk rank
//   [6250, 18750)   : featn = bf16(feat * norm_src)
// ---------------------------------------------------------------------------
__global__ __launch_bounds__(256)
void pre2_kernel(const int* __restrict__ src, const int* __restrict__ dst,
                 const unsigned* __restrict__ row_ptr, const unsigned* __restrict__ p_in,
                 const ushort* __restrict__ rank16, unsigned* __restrict__ edge_src,
                 const float* __restrict__ feat, const unsigned* __restrict__ deg_out,
                 ushort* __restrict__ featn) {
    const int b = blockIdx.x;
    if (b < EDGE_BLOCKS) {
        int e = b * 256 + threadIdx.x;
        int d = dst[e];
        int c = e / CHUNK_E;
        unsigned pos = row_ptr[d] + p_in[(size_t)c * N_NODES + d] + (unsigned)rank16[e];
        edge_src[pos] = (unsigned)src[e];
    } else {
        int id = (b - EDGE_BLOCKS) * 256 + threadIdx.x;   // exact N_NODES*32
        int row = id >> 5;
        float ns = rsqrtf(fmaxf((float)deg_out[row], 1.f));
        float4 v = ((const float4*)feat)[id];
        ushort4 o;
        o.x = (ushort)f2bf(v.x * ns);
        o.y = (ushort)f2bf(v.y * ns);
        o.z = (ushort)f2bf(v.z * ns);
        o.w = (ushort)f2bf(v.w * ns);
        ((ushort4*)featn)[id] = o;
    }
}

// ---------------------------------------------------------------------------
// Kernel 6: row-per-wave gather SpMM over bf16 featn -> aggb (bf16)
// ---------------------------------------------------------------------------
__global__ __launch_bounds__(256)
void spmm_kernel(const ushort* __restrict__ featn,
                 const unsigned* __restrict__ row_ptr, const unsigned* __restrict__ edge_src,
                 unsigned* __restrict__ aggb_u32) {
    int gw = (blockIdx.x * 256 + threadIdx.x) >> 6;
    int lane = threadIdx.x & 63;
    if (gw >= N_NODES) return;
    unsigned beg = row_ptr[gw], end = row_ptr[gw + 1];
    float a0 = 0.f, a1 = 0.f;
    unsigned e = beg;
    for (; e + 4 <= end; e += 4) {
        unsigned s0 = edge_src[e + 0];
        unsigned s1 = edge_src[e + 1];
        unsigned s2 = edge_src[e + 2];
        unsigned s3 = edge_src[e + 3];
        unsigned v0 = *(const unsigned*)(featn + (size_t)s0 * IN_DIM + 2 * lane);
        unsigned v1 = *(const unsigned*)(featn + (size_t)s1 * IN_DIM + 2 * lane);
        unsigned v2 = *(const unsigned*)(featn + (size_t)s2 * IN_DIM + 2 * lane);
        unsigned v3 = *(const unsigned*)(featn + (size_t)s3 * IN_DIM + 2 * lane);
        a0 += __builtin_bit_cast(float, v0 << 16);
        a1 += __builtin_bit_cast(float, v0 & 0xffff0000u);
        a0 += __builtin_bit_cast(float, v1 << 16);
        a1 += __builtin_bit_cast(float, v1 & 0xffff0000u);
        a0 += __builtin_bit_cast(float, v2 << 16);
        a1 += __builtin_bit_cast(float, v2 & 0xffff0000u);
        a0 += __builtin_bit_cast(float, v3 << 16);
        a1 += __builtin_bit_cast(float, v3 & 0xffff0000u);
    }
    for (; e < end; ++e) {
        unsigned s = edge_src[e];
        unsigned v = *(const unsigned*)(featn + (size_t)s * IN_DIM + 2 * lane);
        a0 += __builtin_bit_cast(float, v << 16);
        a1 += __builtin_bit_cast(float, v & 0xffff0000u);
    }
    float nd = rsqrtf(fmaxf((float)(end - beg), 1.0f));
    unsigned lo = (unsigned)(ushort)f2bf(a0 * nd);
    unsigned hi = (unsigned)(ushort)f2bf(a1 * nd);
    aggb_u32[(size_t)gw * (IN_DIM / 2) + lane] = lo | (hi << 16);
}

// ---------------------------------------------------------------------------
// Kernel 7: GEMM1 + LN + ReLU -> lnb (bf16, MFMA C-fragment layout)
// 512 threads = 8 waves; B staged once in 64 KB LDS; barrier-free main loop.
// ---------------------------------------------------------------------------
__global__ __launch_bounds__(512, 2)
void gemm1_ln_kernel(const ushort* __restrict__ aggb, const ushort* __restrict__ Wfrag,
                     const float* __restrict__ bvec, const float* __restrict__ gamma,
                     const float* __restrict__ beta, ushort* __restrict__ lnb) {
    __shared__ __align__(16) ushort Blds[32768];   // 64 KB
    const int tid = threadIdx.x;
    #pragma unroll
    for (int i = 0; i < 8; ++i)
        ((uint4*)Blds)[tid + i * 512] = ((const uint4*)Wfrag)[tid + i * 512];
    __syncthreads();

    const int lane = tid & 63;
    const int c = lane & 15, g = lane >> 4;
    const int gw = blockIdx.x * 8 + (tid >> 6);

    float bb[16], ga[16], be[16];
    #pragma unroll
    for (int n = 0; n < 16; ++n) {
        bb[n] = bvec[n * 16 + c];
        ga[n] = gamma[n * 16 + c];
        be[n] = beta[n * 16 + c];
    }

    for (int t = gw; t < NT; t += 4096) {
        const int r0 = t * 16;
        bf16x8 A[4];
        #pragma unroll
        for (int ks = 0; ks < 4; ++ks)
            A[ks] = *(const bf16x8*)(aggb + (size_t)(r0 + c) * IN_DIM + ks * 32 + g * 8);

        f32x4 acc[16];
        #pragma unroll
        for (int n = 0; n < 16; ++n) {
            acc[n] = (f32x4){bb[n], bb[n], bb[n], bb[n]};
            #pragma unroll
            for (int ks = 0; ks < 4; ++ks) {
                bf16x8 b = *(const bf16x8*)(Blds + ((n * 4 + ks) * 64 + lane) * 8);
                acc[n] = __builtin_amdgcn_mfma_f32_16x16x32_bf16(A[ks], b, acc[n], 0, 0, 0);
            }
        }

        float s1[4], s2[4];
        #pragma unroll
        for (int j = 0; j < 4; ++j) { s1[j] = 0.f; s2[j] = 0.f; }
        #pragma unroll
        for (int n = 0; n < 16; ++n) {
            #pragma unroll
            for (int j = 0; j < 4; ++j) {
                s1[j] += acc[n][j];
                s2[j] = fmaf(acc[n][j], acc[n][j], s2[j]);
            }
        }
        #pragma unroll
        for (int m = 1; m <= 8; m <<= 1) {
            #pragma unroll
            for (int j = 0; j < 4; ++j) {
                s1[j] += __shfl_xor(s1[j], m, 64);
                s2[j] += __shfl_xor(s2[j], m, 64);
            }
        }
        float mu[4], rstd[4];
        #pragma unroll
        for (int j = 0; j < 4; ++j) {
            mu[j] = s1[j] * (1.f / HID_DIM);
            float var = s2[j] * (1.f / HID_DIM) - mu[j] * mu[j];
            rstd[j] = rsqrtf(var + LN_EPS);
        }

        #pragma unroll
        for (int n = 0; n < 16; ++n) {
            ushort4 o;
            o.x = (ushort)f2bf(fmaxf(fmaf((acc[n][0] - mu[0]) * rstd[0], ga[n], be[n]), 0.f));
            o.y = (ushort)f2bf(fmaxf(fmaf((acc[n][1] - mu[1]) * rstd[1], ga[n], be[n]), 0.f));
            o.z = (ushort)f2bf(fmaxf(fmaf((acc[n][2] - mu[2]) * rstd[2], ga[n], be[n]), 0.f));
            o.w = (ushort)f2bf(fmaxf(fmaf((acc[n][3] - mu[3]) * rstd[3], ga[n], be[n]), 0.f));
            *(ushort4*)(lnb + ((size_t)(t * 16 + n) * 64 + lane) * 4) = o;
        }
    }
}

// ---------------------------------------------------------------------------
// Kernel 8: GEMM2 (feat @ skipW) + lnb + skip_b -> out (f32 row-major)
// ---------------------------------------------------------------------------
__global__ __launch_bounds__(512, 2)
void gemm2_kernel(const ushort* __restrict__ lnb, const float* __restrict__ feat,
                  const ushort* __restrict__ sWfrag, const float* __restrict__ skipb,
                  float* __restrict__ out) {
    __shared__ __align__(16) ushort Blds[32768];   // 64 KB
    const int tid = threadIdx.x;
    #pragma unroll
    for (int i = 0; i < 8; ++i)
        ((uint4*)Blds)[tid + i * 512] = ((const uint4*)sWfrag)[tid + i * 512];
    __syncthreads();

    const int lane = tid & 63;
    const int c = lane & 15, g = lane >> 4;
    const int gw = blockIdx.x * 8 + (tid >> 6);

    float sb[16];
    #pragma unroll
    for (int n = 0; n < 16; ++n) sb[n] = skipb[n * 16 + c];

    for (int t = gw; t < NT; t += 4096) {
        const int r0 = t * 16;
        bf16x8 A[4];
        #pragma unroll
        for (int ks = 0; ks < 4; ++ks) {
            const float* fp = feat + (size_t)(r0 + c) * IN_DIM + ks * 32 + g * 8;
            float4 u = *(const float4*)fp;
            float4 v = *(const float4*)(fp + 4);
            bf16x8 a;
            a[0] = f2bf(u.x); a[1] = f2bf(u.y); a[2] = f2bf(u.z); a[3] = f2bf(u.w);
            a[4] = f2bf(v.x); a[5] = f2bf(v.y); a[6] = f2bf(v.z); a[7] = f2bf(v.w);
            A[ks] = a;
        }

        f32x4 acc[16];
        #pragma unroll
        for (int n = 0; n < 16; ++n) {
            ushort4 l = *(const ushort4*)(lnb + ((size_t)(t * 16 + n) * 64 + lane) * 4);
            acc[n] = (f32x4){bf2f(l.x), bf2f(l.y), bf2f(l.z), bf2f(l.w)};
            #pragma unroll
            for (int ks = 0; ks < 4; ++ks) {
                bf16x8 b = *(const bf16x8*)(Blds + ((n * 4 + ks) * 64 + lane) * 8);
                acc[n] = __builtin_amdgcn_mfma_f32_16x16x32_bf16(A[ks], b, acc[n], 0, 0, 0);
            }
        }

        #pragma unroll
        for (int n = 0; n < 16; ++n) {
            #pragma unroll
            for (int j = 0; j < 4; ++j)
                out[(size_t)(r0 + g * 4 + j) * HID_DIM + n * 16 + c] = acc[n][j] + sb[n];
        }
    }
}

// ---------------------------------------------------------------------------
extern "C" void kernel_launch(void* const* d_in, const int* in_sizes, int n_in,
                              void* d_out, int out_size, void* d_ws, size_t ws_size,
                              hipStream_t stream) {
    const float* feat  = (const float*)d_in[0];
    const int*   src   = (const int*)d_in[1];
    const int*   dst   = (const int*)d_in[2];
    const float* W     = (const float*)d_in[3];
    const float* bvec  = (const float*)d_in[4];
    const float* gamma = (const float*)d_in[5];
    const float* beta  = (const float*)d_in[6];
    const float* skipW = (const float*)d_in[7];
    const float* skipb = (const float*)d_in[8];
    float* out = (float*)d_out;

    // workspace, peak ≈ 77 MB (same footprint as rounds 6/7, proven):
    // [Wfrag 64K][sWfrag 64K][aggb 25.6M][xbase region, 51.2M:
    //    featn 25.6M (p_out 12.8M aliases it; dead before fcvt writes featn)
    //  | edge_src 6.4M | rank16 3.2M | p_in 12.8M | deg_out .4 | deg_in .4
    //  | row_ptr .4 ]
    // lnb (51.2M bf16 C-frag) aliases xbase — all members dead before gemm1.
    char* ws = (char*)d_ws;
    ushort*   Wfrag    = (ushort*)ws;                               // 64 KB
    ushort*   sWfrag   = Wfrag + 32768;                             // 64 KB
    ushort*   aggb     = sWfrag + 32768;                            // 25.6 MB
    char*     xbase    = (char*)(aggb + (size_t)N_NODES * IN_DIM);
    ushort*   featn    = (ushort*)xbase;                            // 25.6 MB
    unsigned* p_out    = (unsigned*)xbase;                          // 12.8 MB (alias featn)
    unsigned* edge_src = (unsigned*)(featn + (size_t)N_NODES * IN_DIM); // 6.4 MB
    ushort*   rank16   = (ushort*)(edge_src + N_EDGES);             // 3.2 MB
    unsigned* p_in     = (unsigned*)(rank16 + N_EDGES);             // 12.8 MB
    unsigned* deg_out  = p_in + (size_t)NCHUNK * N_NODES;           // 400 KB
    unsigned* deg_in   = deg_out + N_NODES;                         // 400 KB
    unsigned* row_ptr  = deg_in + N_NODES;                          // 400 KB + pad
    ushort*   lnb      = (ushort*)xbase;                            // 51.2 MB alias

    wcvt_kernel<<<32, 256, 0, stream>>>(W, skipW, Wfrag, sWfrag);

    hist_kernel<<<2 * HBLK, 1024, 0, stream>>>(src, dst, p_out, p_in, rank16);

    prefix_kernel<<<(N_NODES + 255) / 256, 256, 0, stream>>>(p_out, p_in, deg_out, deg_in);

    scan_kernel<<<1, 1024, 0, stream>>>(deg_in, row_ptr);

    pre2_kernel<<<EDGE_BLOCKS + FCVT_BLOCKS, 256, 0, stream>>>(
        src, dst, row_ptr, p_in, rank16, edge_src, feat, deg_out, featn);

    spmm_kernel<<<(N_NODES * 64 + 255) / 256, 256, 0, stream>>>(featn, row_ptr, edge_src,
                                                                (unsigned*)aggb);

    gemm1_ln_kernel<<<512, 512, 0, stream>>>(aggb, Wfrag, bvec, gamma, beta, lnb);

    gemm2_kernel<<<512, 512, 0, stream>>>(lnb, feat, sWfrag, skipb, out);
}